// Round 6
// baseline (2554.631 us; speedup 1.0000x reference)
//
#include <hip/hip_runtime.h>
#include <math.h>

#define B 64
#define H 512
#define MAXN 512
#define U 512
#define MM 32
#define IN_SZ 543      // H + M - 1
#define DEC_STRIDE 544

// ---- d_out layout (floats) ----
#define PTR_OFF 0
#define PTR_SZ (B*MAXN*MM)            // 1,048,576
#define CLOSS_OFF (PTR_OFF + PTR_SZ)  // 1,048,576
#define ENC_OFF (CLOSS_OFF + 1)       // 1,048,577  (NOT 16B aligned)
#define ENC_SZ (B*MAXN*H)             // 16,777,216
#define ADJ_OFF (ENC_OFF + ENC_SZ)    // 17,825,793

// ---- ws layout (floats) ----
#define EP_OFF 0
#define EP_SZ (B*MAXN*U)              // 16,777,216
#define GP_OFF (EP_OFF + EP_SZ)
#define GP_SZ (4*3*B*H)               // 393,216
#define HID0_OFF (GP_OFF + GP_SZ)
#define HID1_OFF (HID0_OFF + B*H)
#define COV_OFF  (HID1_OFF + B*H)
#define DEC_OFF  (COV_OFF + B*MAXN)
#define CL_OFF   (DEC_OFF + B*DEC_STRIDE)
#define OFFS_OFF (CL_OFF + 64)
#define W2T_OFF  (OFFS_OFF + 64)      // 512x512 transposed W2

typedef short bf16x8 __attribute__((ext_vector_type(8)));
typedef float f32x4  __attribute__((ext_vector_type(4)));

__device__ __forceinline__ float tanh_fast(float x){
    float e = __builtin_amdgcn_exp2f(x * 2.885390081777927f);
    return 1.0f - 2.0f * __builtin_amdgcn_rcpf(e + 1.0f);
}

__device__ __forceinline__ unsigned short f2bf(float x){
    unsigned int u = __float_as_uint(x);
    u = (u + 0x7fffu + ((u >> 16) & 1u)) >> 16;
    return (unsigned short)u;
}

// ---------------- init: zero state + offsets + W2 transpose ----------------
__global__ void k_init(float* __restrict__ ws, float* __restrict__ out,
                       const float* __restrict__ hg, const int* __restrict__ lengths,
                       const float* __restrict__ W2){
    int gid = blockIdx.x*256 + threadIdx.x;
    int nth = gridDim.x*256;
    float* ptr = out + PTR_OFF;
    for (int i=gid;i<PTR_SZ;i+=nth) ptr[i]=0.f;
    float* dec = ws + DEC_OFF;
    for (int i=gid;i<B*DEC_STRIDE;i+=nth) dec[i]=0.f;
    float* cov = ws + COV_OFF;
    float* hid0 = ws + HID0_OFF;
    for (int i=gid;i<B*H;i+=nth){ cov[i]=0.f; hid0[i]=hg[i]; }
    float* w2t = ws + W2T_OFF;
    for (int i=gid;i<512*512;i+=nth){
        int u = i >> 9, k = i & 511;
        w2t[k*512 + u] = W2[i];
    }
    if (gid<64) (ws+CL_OFF)[gid]=0.f;
    if (gid==0){
        int* offs=(int*)(ws+OFFS_OFF); int acc=0;
        for(int b=0;b<B;b++){ offs[b]=acc; acc+=lengths[b]; }
    }
}

// ---------------- gather enc ----------------
__global__ __launch_bounds__(256) void k_gather(const float* __restrict__ h,
        const int* __restrict__ lengths, const float* __restrict__ offs_f,
        float* __restrict__ enc){
    const int* offs = (const int*)offs_f;
    int t = threadIdx.x;
    int row = blockIdx.x*2 + (t>>7);
    int c = (t&127)*4;
    int b = row >> 9, n = row & 511;
    int len = lengths[b];
    float4 v = make_float4(0.f,0.f,0.f,0.f);
    if (n < len){
        const float* p = h + (size_t)(offs[b]+n)*H + c;
        v = *(const float4*)p;
    }
    float* q = enc + (size_t)row*H + c;
    q[0]=v.x; q[1]=v.y; q[2]=v.z; q[3]=v.w;
}

// ---------------- ep = enc @ W1^T via split-bf16 MFMA (3-product) ----------------
// C = AH*BH + AH*BL + AL*BH ; error ~2^-18 relative (AL*BL dropped)
__global__ __launch_bounds__(256) void k_gemm_mfma(const float* __restrict__ enc,
        const float* __restrict__ W1, float* __restrict__ ep){
    __shared__ unsigned short sAH[128][40];
    __shared__ unsigned short sAL[128][40];
    __shared__ unsigned short sBH[128][40];
    __shared__ unsigned short sBL[128][40];
    int tid = threadIdx.x;
    int bm = blockIdx.x >> 2, bn = blockIdx.x & 3;
    int r0 = bm*128, u0 = bn*128;
    int wid = tid>>6, lane = tid&63;
    int wr = wid>>1, wc = wid&1;
    int lr = lane&15, lk = (lane>>4)*8;
    f32x4 acc[4][4];
#pragma unroll
    for (int i=0;i<4;i++)
#pragma unroll
        for (int j=0;j<4;j++) acc[i][j] = (f32x4){0.f,0.f,0.f,0.f};
    int rowA = tid>>2, seg = tid&3;
    for (int k0=0;k0<512;k0+=32){
#pragma unroll
        for (int half=0; half<2; ++half){
            int row = rowA + half*64;
            // A tile: enc (misaligned base -> scalar loads), convert to hi/lo bf16
            const float* asrc = &enc[(size_t)(r0+row)*512 + k0 + seg*8];
            bf16x8 vh, vl;
#pragma unroll
            for (int j=0;j<8;j++){
                float x = asrc[j];
                unsigned short hb = f2bf(x);
                float hf = __uint_as_float(((unsigned int)hb)<<16);
                vh[j] = (short)hb;
                vl[j] = (short)f2bf(x - hf);
            }
            *(bf16x8*)&sAH[row][seg*8] = vh;
            *(bf16x8*)&sAL[row][seg*8] = vl;
            // B tile: W1 (aligned), float4 loads
            const float* bsrc = &W1[(size_t)(u0+row)*512 + k0 + seg*8];
            float4 b0 = *(const float4*)bsrc;
            float4 b1 = *(const float4*)(bsrc+4);
            float xb[8] = {b0.x,b0.y,b0.z,b0.w,b1.x,b1.y,b1.z,b1.w};
            bf16x8 wh, wl;
#pragma unroll
            for (int j=0;j<8;j++){
                unsigned short hb = f2bf(xb[j]);
                float hf = __uint_as_float(((unsigned int)hb)<<16);
                wh[j] = (short)hb;
                wl[j] = (short)f2bf(xb[j] - hf);
            }
            *(bf16x8*)&sBH[row][seg*8] = wh;
            *(bf16x8*)&sBL[row][seg*8] = wl;
        }
        __syncthreads();
        bf16x8 aH[4], aL[4], bH[4], bL[4];
#pragma unroll
        for (int f=0; f<4; f++){
            aH[f] = *(const bf16x8*)&sAH[wr*64+f*16+lr][lk];
            aL[f] = *(const bf16x8*)&sAL[wr*64+f*16+lr][lk];
            bH[f] = *(const bf16x8*)&sBH[wc*64+f*16+lr][lk];
            bL[f] = *(const bf16x8*)&sBL[wc*64+f*16+lr][lk];
        }
#pragma unroll
        for (int mf=0;mf<4;mf++){
#pragma unroll
            for (int nf=0;nf<4;nf++){
                acc[mf][nf] = __builtin_amdgcn_mfma_f32_16x16x32_bf16(aH[mf], bH[nf], acc[mf][nf], 0,0,0);
                acc[mf][nf] = __builtin_amdgcn_mfma_f32_16x16x32_bf16(aH[mf], bL[nf], acc[mf][nf], 0,0,0);
                acc[mf][nf] = __builtin_amdgcn_mfma_f32_16x16x32_bf16(aL[mf], bH[nf], acc[mf][nf], 0,0,0);
            }
        }
        __syncthreads();
    }
    // D layout (m89-verified): col = lane&15, row = (lane>>4)*4 + reg
#pragma unroll
    for (int mf=0;mf<4;mf++){
#pragma unroll
        for (int nf=0;nf<4;nf++){
#pragma unroll
            for (int r=0;r<4;r++){
                int row = r0 + wr*64 + mf*16 + (lane>>4)*4 + r;
                int col = u0 + wc*64 + nf*16 + lr;
                ep[(size_t)row*512 + col] = acc[mf][nf][r];
            }
        }
    }
}

// ---------------- GRU partial dots (proven R5): 512 blocks, 4-way K-split ----------------
__global__ __launch_bounds__(256) void k_gruP(const float* __restrict__ dec_in,
        const float* __restrict__ hid_in,
        const float* __restrict__ w_ih, const float* __restrict__ w_hh,
        float* __restrict__ gp){
    __shared__ float As[64][36];
    __shared__ float Ws[12][36];
    int tid=threadIdx.x, b=tid&63, q=tid>>6;
    int s = blockIdx.x >> 7;
    int h0 = (int)(blockIdx.x & 127) * 4;
    const float* xs; int xstride, kbeg, kend; const float* W; int wstride;
    if (s==0){ xs=dec_in; xstride=DEC_STRIDE; kbeg=0;   kend=288;   W=w_ih; wstride=IN_SZ; }
    else if(s==1){ xs=dec_in; xstride=DEC_STRIDE; kbeg=288; kend=IN_SZ; W=w_ih; wstride=IN_SZ; }
    else if(s==2){ xs=hid_in; xstride=512; kbeg=0;   kend=256; W=w_hh; wstride=512; }
    else         { xs=hid_in; xstride=512; kbeg=256; kend=512; W=w_hh; wstride=512; }
    float a0=0.f,a1=0.f,a2=0.f;
    for (int k0=kbeg; k0<kend; k0+=32){
        for (int it=0;it<2;it++){
            int idx=tid+it*256; int row=idx>>3, c=idx&7; int k=k0+c*4;
            float4 v=make_float4(0.f,0.f,0.f,0.f);
            const float* p=&xs[row*xstride+k];
            if (k+3 < kend) v=*(const float4*)p;
            else { if(k<kend)v.x=p[0]; if(k+1<kend)v.y=p[1]; if(k+2<kend)v.z=p[2]; }
            *(float4*)&As[row][c*4]=v;
        }
        if (tid<96){
            int rr=tid>>3, c=tid&7; int g=rr>>2, qq=rr&3;
            int j=g*512 + h0+qq; int k=k0+c*4;
            float4 v=make_float4(0.f,0.f,0.f,0.f);
            const float* p=&W[(size_t)j*wstride+k];
            if (wstride==512){
                v=*(const float4*)p;
            } else {
                if(k<kend)v.x=p[0]; if(k+1<kend)v.y=p[1];
                if(k+2<kend)v.z=p[2]; if(k+3<kend)v.w=p[3];
            }
            *(float4*)&Ws[rr][c*4]=v;
        }
        __syncthreads();
#pragma unroll
        for (int kk=0;kk<32;kk+=4){
            float4 a=*(const float4*)&As[b][kk];
            float4 w0=*(const float4*)&Ws[q][kk];
            float4 w1=*(const float4*)&Ws[4+q][kk];
            float4 w2=*(const float4*)&Ws[8+q][kk];
            a0 += a.x*w0.x + a.y*w0.y + a.z*w0.z + a.w*w0.w;
            a1 += a.x*w1.x + a.y*w1.y + a.z*w1.z + a.w*w1.w;
            a2 += a.x*w2.x + a.y*w2.y + a.z*w2.z + a.w*w2.w;
        }
        __syncthreads();
    }
    int h = h0 + q;
    gp[((s*3+0)*64+b)*512 + h] = a0;
    gp[((s*3+1)*64+b)*512 + h] = a1;
    gp[((s*3+2)*64+b)*512 + h] = a2;
}

// ---------------- fused step-tail: epilogue + w2h(W2T) + theta + scores + soft ----------------
// 64 blocks (one per b) x 1024 threads
__global__ __launch_bounds__(1024) void k_ss(
        const float* __restrict__ gp, const float* __restrict__ hid_in,
        float* __restrict__ hid_out,
        const float* __restrict__ b_ih, const float* __restrict__ b_hh,
        const float* __restrict__ w2t, const float* __restrict__ Wf,
        const float* __restrict__ bf_,
        const float* __restrict__ wc, const float* __restrict__ v,
        const float* __restrict__ ep, const float* __restrict__ gum,
        const int* __restrict__ lengths, const float* __restrict__ enc,
        float* __restrict__ cov, float* __restrict__ dec_in,
        float* __restrict__ clb, float* __restrict__ pointer,
        float* __restrict__ adj, int step){
    __shared__ float sH[512], sV[512], sC[512], sCov[512];
    __shared__ float sWa[512], sWb[512], sW[512], sSc[512];
    __shared__ float red[512];
    __shared__ int  redi[512];
    const int b = blockIdx.x, tid = threadIdx.x;
    const int wv = tid>>6, lane = tid&63;
    const int len = lengths[b];

    // ---- phase 1: GRU epilogue (t<512) ; stage v/wc/cov (t>=512) ----
    if (tid < 512){
        int h = tid;
        float gI0 = gp[((0*3+0)*64+b)*512+h] + gp[((1*3+0)*64+b)*512+h];
        float gI1 = gp[((0*3+1)*64+b)*512+h] + gp[((1*3+1)*64+b)*512+h];
        float gI2 = gp[((0*3+2)*64+b)*512+h] + gp[((1*3+2)*64+b)*512+h];
        float gH0 = gp[((2*3+0)*64+b)*512+h] + gp[((3*3+0)*64+b)*512+h];
        float gH1 = gp[((2*3+1)*64+b)*512+h] + gp[((3*3+1)*64+b)*512+h];
        float gH2 = gp[((2*3+2)*64+b)*512+h] + gp[((3*3+2)*64+b)*512+h];
        float gi0=gI0+b_ih[h],      gh0=gH0+b_hh[h];
        float gi1=gI1+b_ih[512+h],  gh1=gH1+b_hh[512+h];
        float gi2=gI2+b_ih[1024+h], gh2=gH2+b_hh[1024+h];
        float r=1.f/(1.f+expf(-(gi0+gh0)));
        float z=1.f/(1.f+expf(-(gi1+gh1)));
        float nn=tanhf(gi2 + r*gh2);
        float hv=(1.f-z)*nn + z*hid_in[b*512+h];
        sH[h]=hv;
        hid_out[b*512+h]=hv;
    } else {
        int t2 = tid - 512;
        if (t2 < 128)      *(float4*)&sV[t2*4]         = *(const float4*)&v[t2*4];
        else if (t2 < 256) *(float4*)&sC[(t2-128)*4]   = *(const float4*)&wc[(t2-128)*4];
        else if (t2 < 384) *(float4*)&sCov[(t2-256)*4] = *(const float4*)&cov[b*512+(t2-256)*4];
    }
    __syncthreads();

    // ---- phase 2: w2h, k-split across 1024 threads (coalesced W2T reads) ----
    {
        int u = tid & 511;
        int kb = (tid < 512) ? 0 : 256;
        float acc = 0.f;
#pragma unroll 8
        for (int k=0;k<256;k++) acc += sH[kb+k] * w2t[(size_t)(kb+k)*512 + u];
        if (tid < 512) sWa[u]=acc; else sWb[u]=acc;
    }
    __syncthreads();

    // ---- phase 2.5: combine w2h ; theta on wave 15 ----
    if (tid < 512) sW[tid] = sWa[tid] + sWb[tid];
    if (wv == 15){
        float4 h0 = *(const float4*)&sH[lane*8];
        float4 h1 = *(const float4*)&sH[lane*8+4];
        for (int u=0; u<31; ++u){
            const float4* wr_ = (const float4*)&Wf[(size_t)u*512 + lane*8];
            float4 w0=wr_[0], w1=wr_[1];
            float acc = w0.x*h0.x + w0.y*h0.y + w0.z*h0.z + w0.w*h0.w
                      + w1.x*h1.x + w1.y*h1.y + w1.z*h1.z + w1.w*h1.w;
#pragma unroll
            for (int m=1;m<64;m<<=1) acc += __shfl_xor(acc, m, 64);
            if (lane==0){
                float th = 1.f/(1.f+expf(-(acc + bf_[u])));
                th = (u < step) ? th : 0.f;
                dec_in[b*DEC_STRIDE + 512 + u] = th;
                adj[b*992 + u*32 + step] = th;
            }
        }
    }
    __syncthreads();

    // ---- phase 3: scores (16 waves over rows) ----
    {
        float4 vv0=*(const float4*)&sV[lane*8], vv1=*(const float4*)&sV[lane*8+4];
        float4 cc0=*(const float4*)&sC[lane*8], cc1=*(const float4*)&sC[lane*8+4];
        float4 ww0=*(const float4*)&sW[lane*8], ww1=*(const float4*)&sW[lane*8+4];
        for (int n=wv; n<len; n+=16){
            float cb = sCov[n];
            const float4* rr = (const float4*)&ep[((size_t)b*512+n)*512 + lane*8];
            float4 e0=rr[0], e1=rr[1];
            float acc;
            acc  = tanh_fast(e0.x + ww0.x + cb*cc0.x)*vv0.x;
            acc += tanh_fast(e0.y + ww0.y + cb*cc0.y)*vv0.y;
            acc += tanh_fast(e0.z + ww0.z + cb*cc0.z)*vv0.z;
            acc += tanh_fast(e0.w + ww0.w + cb*cc0.w)*vv0.w;
            acc += tanh_fast(e1.x + ww1.x + cb*cc1.x)*vv1.x;
            acc += tanh_fast(e1.y + ww1.y + cb*cc1.y)*vv1.y;
            acc += tanh_fast(e1.z + ww1.z + cb*cc1.z)*vv1.z;
            acc += tanh_fast(e1.w + ww1.w + cb*cc1.w)*vv1.w;
#pragma unroll
            for (int m=1;m<64;m<<=1) acc += __shfl_xor(acc, m, 64);
            if (lane==0) sSc[n]=acc;
        }
    }
    __syncthreads();

    // ---- phase 4: softmax / coverage / closs / argmax / dec head ----
    int n = tid;
    float e = 0.f;
    if (n < 512){ e = (n < len) ? expf(sSc[n]) : 0.f; red[n] = e; }
    __syncthreads();
    for (int o=256;o>=1;o>>=1){ if (n<o) red[n]+=red[n+o]; __syncthreads(); }
    float Z = red[0];
    __syncthreads();
    float att = 0.f, cvo = 0.f;
    if (n < 512){
        att = e / Z;
        cvo = sCov[n];
        red[n] = fminf(att, cvo);
    }
    __syncthreads();
    for (int o=256;o>=1;o>>=1){ if (n<o) red[n]+=red[n+o]; __syncthreads(); }
    if (tid==0) clb[b] += red[0];
    __syncthreads();
    if (n < 512){
        cov[b*512+n] = cvo + att;
        float lg = logf(att + 1e-12f) + gum[((size_t)step*64+b)*512 + n];
        red[n] = lg; redi[n] = n;
    }
    __syncthreads();
    for (int o=256;o>=1;o>>=1){
        if (n<o && red[n+o]>red[n]){ red[n]=red[n+o]; redi[n]=redi[n+o]; }
        __syncthreads();
    }
    int ns = redi[0];
    if (tid==0) pointer[b*16384 + ns*32 + step] = 1.f;
    if (n < 512) dec_in[b*DEC_STRIDE + n] = enc[((size_t)b*512+ns)*512 + n];
}

__global__ void k_final(const float* __restrict__ closs_b, float* __restrict__ out){
    if (threadIdx.x==0 && blockIdx.x==0){
        float s=0.f;
        for(int b=0;b<B;b++) s+=closs_b[b];
        out[CLOSS_OFF]=s/64.f;
    }
}

extern "C" void kernel_launch(void* const* d_in, const int* in_sizes, int n_in,
                              void* d_out, int out_size, void* d_ws, size_t ws_size,
                              hipStream_t stream){
    const float* h      = (const float*)d_in[0];
    const float* hg     = (const float*)d_in[1];
    const int*   lengths= (const int*)  d_in[2];
    const float* gumbel = (const float*)d_in[3];
    const float* W1     = (const float*)d_in[4];
    const float* W2     = (const float*)d_in[5];
    const float* wc     = (const float*)d_in[6];
    const float* v      = (const float*)d_in[7];
    const float* w_ih   = (const float*)d_in[8];
    const float* w_hh   = (const float*)d_in[9];
    const float* b_ih   = (const float*)d_in[10];
    const float* b_hh   = (const float*)d_in[11];
    const float* Wf     = (const float*)d_in[12];
    const float* bf     = (const float*)d_in[13];
    float* out = (float*)d_out;
    float* ws  = (float*)d_ws;
    float* enc = out + ENC_OFF;
    float* adj = out + ADJ_OFF;
    float* pointer = out + PTR_OFF;
    float* ep   = ws + EP_OFF;
    float* gp   = ws + GP_OFF;
    float* hidA = ws + HID0_OFF;
    float* hidB = ws + HID1_OFF;
    float* cov  = ws + COV_OFF;
    float* dec  = ws + DEC_OFF;
    float* clb  = ws + CL_OFF;
    float* w2t  = ws + W2T_OFF;

    hipLaunchKernelGGL(k_init,     dim3(512),  dim3(256), 0, stream, ws, out, hg, lengths, W2);
    hipLaunchKernelGGL(k_gather,   dim3(16384),dim3(256), 0, stream, h, lengths, ws+OFFS_OFF, enc);
    hipLaunchKernelGGL(k_gemm_mfma,dim3(1024), dim3(256), 0, stream, enc, W1, ep);

    for (int i=0;i<MM;i++){
        const float* hin = (i&1)? hidB : hidA;
        float*       hout= (i&1)? hidA : hidB;
        hipLaunchKernelGGL(k_gruP, dim3(512), dim3(256), 0, stream,
                           dec, hin, w_ih, w_hh, gp);
        hipLaunchKernelGGL(k_ss,   dim3(64),  dim3(1024), 0, stream,
                           gp, hin, hout, b_ih, b_hh, w2t, Wf, bf, wc, v,
                           ep, gumbel, lengths, enc, cov, dec, clb, pointer, adj, i);
    }
    hipLaunchKernelGGL(k_final, dim3(1), dim3(64), 0, stream, clb, out);
}